// Round 7
// baseline (3761.303 us; speedup 1.0000x reference)
//
#include <hip/hip_runtime.h>
#include <math.h>

#define KTOK  32
#define DM    64
#define DH    16
#define NH    4
#define DFF   128
#define KVSTR 36   // 144B rows -> 16B-aligned float4 reads
#define QB    8    // queries per block (256 threads = 8 x 32-lane query slots)

__global__ __launch_bounds__(256, 2)
void ff_kernel(
    const int*   __restrict__ qidx,
    const int*   __restrict__ offs,
    const float* __restrict__ vals,
    const float* __restrict__ gscale,
    const int*   __restrict__ NxP,
    const int*   __restrict__ NyP,
    const int*   __restrict__ NtP,
    const float* __restrict__ lgam,
    const float* __restrict__ Wp,   const float* __restrict__ bp,
    const float* __restrict__ Wqkv, const float* __restrict__ bqkv,
    const float* __restrict__ Wo,   const float* __restrict__ bo,
    const float* __restrict__ W1w,  const float* __restrict__ b1w,
    const float* __restrict__ W2w,  const float* __restrict__ b2w,
    const float* __restrict__ ln1g, const float* __restrict__ ln1b,
    const float* __restrict__ ln2g, const float* __restrict__ ln2b,
    const float* __restrict__ hg,   const float* __restrict__ hb,
    const float* __restrict__ hW1,  const float* __restrict__ hb1,
    const float* __restrict__ hW2,  const float* __restrict__ hb2,
    float* __restrict__ out)
{
    __shared__ float kv[QB][KTOK][KVSTR];   // 36864 B
    __shared__ float wbig[4096];            // 16384 B weight staging buffer

    const int tid   = threadIdx.x;
    const int qslot = tid >> 5;      // 0..7: which query in this block
    const int kk    = tid & 31;      // token index this lane owns
    const int b     = blockIdx.x * QB + qslot;

    const int Nx = NxP[0], Ny = NyP[0], Nt = NtP[0];
    const int NyNt = Ny * Nt;

    // ---- decode query cell ----
    const int q  = qidx[b];
    const int i0 = q / NyNt;
    const int r0 = q - i0 * NyNt;
    const int j0 = r0 / Nt;
    const int t0 = r0 - j0 * Nt;

    const int di = offs[kk*3+0], dj = offs[kk*3+1], dk = offs[kk*3+2];
    int I = i0 + di; if (I >= Nx) I -= Nx;
    int J = j0 + dj; if (J >= Ny) J -= Ny;
    int Kc = t0 + dk; if (Kc >= Nt) Kc -= Nt;
    const float val = vals[I*NyNt + J*Nt + Kc];

    const float r1 = (float)di * gscale[0] * expf(lgam[0]);
    const float r2 = (float)dj * gscale[1] * expf(lgam[1]);
    const float r3 = (float)dk * gscale[2] * expf(lgam[2]);

    // ---- input projection (tiny; scalar path fine) ----
    float h[DM];
#pragma unroll
    for (int d = 0; d < DM; ++d)
        h[d] = bp[d] + Wp[d*4+0]*r1 + Wp[d*4+1]*r2 + Wp[d*4+2]*r3 + Wp[d*4+3]*val;

    // ================= transformer layers =================
    for (int l = 0; l < 2; ++l) {
        const float* Wq  = Wqkv + l*(3*DM)*DM;
        const float* bq  = bqkv + l*(3*DM);
        const float* WoL = Wo   + l*DM*DM;

        float xacc[DM];
#pragma unroll
        for (int dp = 0; dp < DM; ++dp) xacc[dp] = h[dp] + bo[l*DM+dp];

        for (int hh = 0; hh < NH; ++hh) {
            __syncthreads();   // prior phase done with wbig & kv

            // ---- stage Wq/Wk/Wv head slices (3x4KB contig) + Wo column slice (4KB strided) ----
            {
                float4* dst = (float4*)wbig;
                dst[tid]       = ((const float4*)(Wq + (hh*DH)*DM       ))[tid];
                dst[256 + tid] = ((const float4*)(Wq + (DM   + hh*DH)*DM))[tid];
                dst[512 + tid] = ((const float4*)(Wq + (2*DM + hh*DH)*DM))[tid];
                // Wo slice: row r=tid>>2 (64 rows), float4 c=tid&3 of 16 cols at hh*16
                dst[768 + tid] = *(const float4*)(WoL + (tid>>2)*DM + hh*DH + (tid&3)*4);
            }
            __syncthreads();

            // ---- k,v rows -> kv LDS (weights via broadcast ds_read_b128) ----
            for (int t = 0; t < DH; ++t) {
                const float4* wk4 = (const float4*)(wbig + 1024 + t*DM);
                const float4* wv4 = (const float4*)(wbig + 2048 + t*DM);
                float ak0 = bq[DM+hh*DH+t],   ak1 = 0.f;
                float av0 = bq[2*DM+hh*DH+t], av1 = 0.f;
#pragma unroll
                for (int d4 = 0; d4 < 16; ++d4) {
                    float4 wk = wk4[d4], wv = wv4[d4];
                    ak0 = fmaf(h[d4*4+0], wk.x, ak0);
                    ak1 = fmaf(h[d4*4+1], wk.y, ak1);
                    ak0 = fmaf(h[d4*4+2], wk.z, ak0);
                    ak1 = fmaf(h[d4*4+3], wk.w, ak1);
                    av0 = fmaf(h[d4*4+0], wv.x, av0);
                    av1 = fmaf(h[d4*4+1], wv.y, av1);
                    av0 = fmaf(h[d4*4+2], wv.z, av0);
                    av1 = fmaf(h[d4*4+3], wv.w, av1);
                }
                kv[qslot][kk][t]    = ak0 + ak1;
                kv[qslot][kk][DH+t] = av0 + av1;
            }
            __syncthreads();

            // ---- q projection (reads wq_s in wbig[0:1024]) ----
            float qh[DH];
#pragma unroll
            for (int t = 0; t < DH; ++t) {
                const float4* wq4 = (const float4*)(wbig + t*DM);
                float a0 = bq[hh*DH + t], a1 = 0.f;
#pragma unroll
                for (int d4 = 0; d4 < 16; ++d4) {
                    float4 w = wq4[d4];
                    a0 = fmaf(h[d4*4+0], w.x, a0);
                    a1 = fmaf(h[d4*4+1], w.y, a1);
                    a0 = fmaf(h[d4*4+2], w.z, a0);
                    a1 = fmaf(h[d4*4+3], w.w, a1);
                }
                qh[t] = (a0 + a1) * 0.25f;   // fold 1/sqrt(Dh)
            }

            // ---- scores ----
            float sc[KTOK];
            float mx = -1e30f;
#pragma unroll
            for (int kx = 0; kx < KTOK; ++kx) {
                const float4* kr = (const float4*)&kv[qslot][kx][0];
                float s0 = 0.f, s1 = 0.f;
#pragma unroll
                for (int t4 = 0; t4 < 4; ++t4) {
                    float4 k4 = kr[t4];
                    s0 = fmaf(qh[t4*4+0], k4.x, s0);
                    s1 = fmaf(qh[t4*4+1], k4.y, s1);
                    s0 = fmaf(qh[t4*4+2], k4.z, s0);
                    s1 = fmaf(qh[t4*4+3], k4.w, s1);
                }
                sc[kx] = s0 + s1;
                mx = fmaxf(mx, sc[kx]);
            }
            float den = 0.f;
#pragma unroll
            for (int kx = 0; kx < KTOK; ++kx) {
                float e = expf(sc[kx] - mx);
                sc[kx] = e; den += e;
            }
            const float inv = 1.f / den;

            // ---- PV ----
            float oh[DH];
#pragma unroll
            for (int t = 0; t < DH; ++t) oh[t] = 0.f;
#pragma unroll
            for (int kx = 0; kx < KTOK; ++kx) {
                const float w = sc[kx] * inv;
                const float4* vr = (const float4*)&kv[qslot][kx][DH];
#pragma unroll
                for (int t4 = 0; t4 < 4; ++t4) {
                    float4 v4 = vr[t4];
                    oh[t4*4+0] = fmaf(w, v4.x, oh[t4*4+0]);
                    oh[t4*4+1] = fmaf(w, v4.y, oh[t4*4+1]);
                    oh[t4*4+2] = fmaf(w, v4.z, oh[t4*4+2]);
                    oh[t4*4+3] = fmaf(w, v4.w, oh[t4*4+3]);
                }
            }

            // ---- fold this head's o into xacc via staged Wo slice ----
#pragma unroll
            for (int dp = 0; dp < DM; ++dp) {
                const float4* w4 = (const float4*)(wbig + 3072 + dp*DH);
                float4 wa = w4[0], wb = w4[1], wc = w4[2], wd = w4[3];
                float s0 = 0.f, s1 = 0.f;
                s0 = fmaf(oh[0],  wa.x, s0); s1 = fmaf(oh[1],  wa.y, s1);
                s0 = fmaf(oh[2],  wa.z, s0); s1 = fmaf(oh[3],  wa.w, s1);
                s0 = fmaf(oh[4],  wb.x, s0); s1 = fmaf(oh[5],  wb.y, s1);
                s0 = fmaf(oh[6],  wb.z, s0); s1 = fmaf(oh[7],  wb.w, s1);
                s0 = fmaf(oh[8],  wc.x, s0); s1 = fmaf(oh[9],  wc.y, s1);
                s0 = fmaf(oh[10], wc.z, s0); s1 = fmaf(oh[11], wc.w, s1);
                s0 = fmaf(oh[12], wd.x, s0); s1 = fmaf(oh[13], wd.y, s1);
                s0 = fmaf(oh[14], wd.z, s0); s1 = fmaf(oh[15], wd.w, s1);
                xacc[dp] += s0 + s1;
            }
        }

        // ---- LN1 ----
        {
            float mean = 0.f;
#pragma unroll
            for (int dp = 0; dp < DM; ++dp) mean += xacc[dp];
            mean *= (1.f/DM);
            float var = 0.f;
#pragma unroll
            for (int dp = 0; dp < DM; ++dp) { float dx = xacc[dp]-mean; var = fmaf(dx,dx,var); }
            var *= (1.f/DM);
            const float rs = rsqrtf(var + 1e-5f);
#pragma unroll
            for (int dp = 0; dp < DM; ++dp)
                h[dp] = (xacc[dp]-mean)*rs*ln1g[l*DM+dp] + ln1b[l*DM+dp];
        }

        // ---- FF in f-quarters: stage W1 quarter (contig) + W2 quarter (strided) ----
        float a2[DM];
#pragma unroll
        for (int dp = 0; dp < DM; ++dp) a2[dp] = h[dp] + b2w[l*DM+dp];
        const float* W1L = W1w + l*DFF*DM;
        const float* W2L = W2w + l*DM*DFF;
        for (int f0 = 0; f0 < DFF; f0 += 32) {
            __syncthreads();   // prior wbig readers done
            {
                float4* dst = (float4*)wbig;
                const float4* s1p = (const float4*)(W1L + f0*DM);   // 2048 floats contig
                dst[tid]       = s1p[tid];
                dst[256 + tid] = s1p[256 + tid];
                // W2 quarter: 64 rows x 32 floats from W2L + dp*128 + f0
                int g = tid;               // g>>3 = row, g&7 = float4 within row
                dst[512 + g] = *(const float4*)(W2L + (g>>3)*DFF + f0 + (g&7)*4);
                g = tid + 256;
                dst[512 + g] = *(const float4*)(W2L + (g>>3)*DFF + f0 + (g&7)*4);
            }
            __syncthreads();

            for (int fc0 = 0; fc0 < 32; fc0 += 8) {
                float a[8];
#pragma unroll
                for (int fc = 0; fc < 8; ++fc) {
                    const float4* w14 = (const float4*)(wbig + (fc0+fc)*DM);
                    float s0 = b1w[l*DFF + f0 + fc0 + fc], s1 = 0.f;
#pragma unroll
                    for (int d4 = 0; d4 < 16; ++d4) {
                        float4 w = w14[d4];
                        s0 = fmaf(h[d4*4+0], w.x, s0);
                        s1 = fmaf(h[d4*4+1], w.y, s1);
                        s0 = fmaf(h[d4*4+2], w.z, s0);
                        s1 = fmaf(h[d4*4+3], w.w, s1);
                    }
                    a[fc] = fmaxf(s0 + s1, 0.f);
                }
#pragma unroll
                for (int dp = 0; dp < DM; ++dp) {
                    const float4* w24 = (const float4*)(wbig + 2048 + dp*32 + fc0);
                    float4 wa = w24[0], wb = w24[1];
                    float u0 = fmaf(a[0], wa.x, fmaf(a[1], wa.y, fmaf(a[2], wa.z, a[3]*wa.w)));
                    float u1 = fmaf(a[4], wb.x, fmaf(a[5], wb.y, fmaf(a[6], wb.z, a[7]*wb.w)));
                    a2[dp] += u0 + u1;
                }
            }
        }

        // ---- LN2 ----
        {
            float mean = 0.f;
#pragma unroll
            for (int dp = 0; dp < DM; ++dp) mean += a2[dp];
            mean *= (1.f/DM);
            float var = 0.f;
#pragma unroll
            for (int dp = 0; dp < DM; ++dp) { float dx = a2[dp]-mean; var = fmaf(dx,dx,var); }
            var *= (1.f/DM);
            const float rs = rsqrtf(var + 1e-5f);
#pragma unroll
            for (int dp = 0; dp < DM; ++dp)
                h[dp] = (a2[dp]-mean)*rs*ln2g[l*DM+dp] + ln2b[l*DM+dp];
        }
    }

    // ================= head: token-mean via shuffle butterfly =================
    float hm[DM];
#pragma unroll
    for (int d = 0; d < DM; ++d) {
        float v = h[d];
        v += __shfl_xor(v, 1,  64);
        v += __shfl_xor(v, 2,  64);
        v += __shfl_xor(v, 4,  64);
        v += __shfl_xor(v, 8,  64);
        v += __shfl_xor(v, 16, 64);   // masks <32: 32-lane query halves stay independent
        hm[d] = v * (1.f/KTOK);
    }
    {
        float mean = 0.f;
#pragma unroll
        for (int d = 0; d < DM; ++d) mean += hm[d];
        mean *= (1.f/DM);
        float var = 0.f;
#pragma unroll
        for (int d = 0; d < DM; ++d) { float dx = hm[d]-mean; var = fmaf(dx,dx,var); }
        var *= (1.f/DM);
        const float rs = rsqrtf(var + 1e-5f);
#pragma unroll
        for (int d = 0; d < DM; ++d)
            hm[d] = (hm[d]-mean)*rs*hg[d] + hb[d];
    }

    // ---- distributed head MLP: lane owns GELU rows kk and kk+32 ----
    float acc = 0.f;
#pragma unroll
    for (int zz = 0; zz < 2; ++zz) {
        const int zi = kk + zz*32;
        const float4* w4 = (const float4*)(hW1 + zi*DM);
        float a0 = hb1[zi], a1 = 0.f;
#pragma unroll
        for (int d4 = 0; d4 < DM/4; ++d4) {
            float4 w = w4[d4];
            a0 = fmaf(hm[d4*4+0], w.x, a0);
            a1 = fmaf(hm[d4*4+1], w.y, a1);
            a0 = fmaf(hm[d4*4+2], w.z, a0);
            a1 = fmaf(hm[d4*4+3], w.w, a1);
        }
        const float a = a0 + a1;
        const float g = 0.5f * a * (1.f + erff(a * 0.70710678118654752f));
        acc = fmaf(g, hW2[zi], acc);
    }
    acc += __shfl_xor(acc, 1,  64);
    acc += __shfl_xor(acc, 2,  64);
    acc += __shfl_xor(acc, 4,  64);
    acc += __shfl_xor(acc, 8,  64);
    acc += __shfl_xor(acc, 16, 64);

    if (kk == 0) out[b] = acc + hb2[0];
}

extern "C" void kernel_launch(void* const* d_in, const int* in_sizes, int n_in,
                              void* d_out, int out_size, void* d_ws, size_t ws_size,
                              hipStream_t stream) {
    const int*   qidx   = (const int*)  d_in[0];
    const int*   offs   = (const int*)  d_in[1];
    const float* vals   = (const float*)d_in[2];
    // d_in[3] coords: unused by the reference
    const float* gscale = (const float*)d_in[4];
    const int*   NxP    = (const int*)  d_in[5];
    const int*   NyP    = (const int*)  d_in[6];
    const int*   NtP    = (const int*)  d_in[7];
    const float* lgam   = (const float*)d_in[8];
    const float* Wp     = (const float*)d_in[9];
    const float* bp     = (const float*)d_in[10];
    const float* Wqkv   = (const float*)d_in[11];
    const float* bqkv   = (const float*)d_in[12];
    const float* Wo     = (const float*)d_in[13];
    const float* bo     = (const float*)d_in[14];
    const float* W1w    = (const float*)d_in[15];
    const float* b1w    = (const float*)d_in[16];
    const float* W2w    = (const float*)d_in[17];
    const float* b2w    = (const float*)d_in[18];
    const float* ln1g   = (const float*)d_in[19];
    const float* ln1b   = (const float*)d_in[20];
    const float* ln2g   = (const float*)d_in[21];
    const float* ln2b   = (const float*)d_in[22];
    const float* hg     = (const float*)d_in[23];
    const float* hb     = (const float*)d_in[24];
    const float* hW1    = (const float*)d_in[25];
    const float* hb1    = (const float*)d_in[26];
    const float* hW2    = (const float*)d_in[27];
    const float* hb2    = (const float*)d_in[28];
    float* outp = (float*)d_out;

    const int B = in_sizes[0];
    dim3 grid(B / QB), block(256);
    hipLaunchKernelGGL(ff_kernel, grid, block, 0, stream,
        qidx, offs, vals, gscale, NxP, NyP, NtP, lgam,
        Wp, bp, Wqkv, bqkv, Wo, bo, W1w, b1w, W2w, b2w,
        ln1g, ln1b, ln2g, ln2b, hg, hb, hW1, hb1, hW2, hb2, outp);
}

// Round 8
// 3097.197 us; speedup vs baseline: 1.2144x; 1.2144x over previous
//
#include <hip/hip_runtime.h>
#include <math.h>

#define KTOK  32
#define DM    64
#define DH    16
#define NH    4
#define DFF   128
#define KVP   20   // kv row stride in floats: 80B, 16B-aligned, 8 start-banks
#define QB    4    // queries per block = 4 waves of 64 lanes

__global__ __launch_bounds__(256, 4)
void ff_kernel(
    const int*   __restrict__ qidx,
    const int*   __restrict__ offs,
    const float* __restrict__ vals,
    const float* __restrict__ gscale,
    const int*   __restrict__ NxP,
    const int*   __restrict__ NyP,
    const int*   __restrict__ NtP,
    const float* __restrict__ lgam,
    const float* __restrict__ Wp,   const float* __restrict__ bp,
    const float* __restrict__ Wqkv, const float* __restrict__ bqkv,
    const float* __restrict__ Wo,   const float* __restrict__ bo,
    const float* __restrict__ W1w,  const float* __restrict__ b1w,
    const float* __restrict__ W2w,  const float* __restrict__ b2w,
    const float* __restrict__ ln1g, const float* __restrict__ ln1b,
    const float* __restrict__ ln2g, const float* __restrict__ ln2b,
    const float* __restrict__ hg,   const float* __restrict__ hb,
    const float* __restrict__ hW1,  const float* __restrict__ hb1,
    const float* __restrict__ hW2,  const float* __restrict__ hb2,
    float* __restrict__ out)
{
    // kv tiles are PER-WAVE private: no block barrier needed for them.
    __shared__ float kvK[QB][KTOK][KVP];   // 10240 B
    __shared__ float kvV[QB][KTOK][KVP];   // 10240 B
    __shared__ float wbig[4096];           // 16384 B block-shared weight stage

    const int tid  = threadIdx.x;
    const int w    = tid >> 6;        // wave = query slot
    const int lane = tid & 63;
    const int half = lane >> 5;       // 0: dims 0..31, 1: dims 32..63
    const int tok  = lane & 31;       // token this lane (pair) owns
    const int hofs = half * 32;       // my dim offset
    const int b    = blockIdx.x * QB + w;

    const int Nx = NxP[0], Ny = NyP[0], Nt = NtP[0];
    const int NyNt = Ny * Nt;

    // ---- decode query cell (uniform per wave) ----
    const int q  = qidx[b];
    const int i0 = q / NyNt;
    const int r0 = q - i0 * NyNt;
    const int j0 = r0 / Nt;
    const int t0 = r0 - j0 * Nt;

    const int di = offs[tok*3+0], dj = offs[tok*3+1], dk = offs[tok*3+2];
    int I = i0 + di; if (I >= Nx) I -= Nx;
    int J = j0 + dj; if (J >= Ny) J -= Ny;
    int Kc = t0 + dk; if (Kc >= Nt) Kc -= Nt;
    const float val = vals[I*NyNt + J*Nt + Kc];

    const float r1 = (float)di * gscale[0] * expf(lgam[0]);
    const float r2 = (float)dj * gscale[1] * expf(lgam[1]);
    const float r3 = (float)dk * gscale[2] * expf(lgam[2]);

    // ---- input projection: lane holds h[hofs .. hofs+32) of its token ----
    float h[32];
#pragma unroll
    for (int i = 0; i < 32; ++i) {
        const int d = hofs + i;
        h[i] = bp[d] + Wp[d*4+0]*r1 + Wp[d*4+1]*r2 + Wp[d*4+2]*r3 + Wp[d*4+3]*val;
    }

    // ================= transformer layers =================
    for (int l = 0; l < 2; ++l) {
        const float* Wq  = Wqkv + l*(3*DM)*DM;
        const float* bq  = bqkv + l*(3*DM);
        const float* WoL = Wo   + l*DM*DM;

        float xacc[32];
#pragma unroll
        for (int i = 0; i < 32; ++i) xacc[i] = h[i] + bo[l*DM + hofs + i];

        for (int hh = 0; hh < NH; ++hh) {
            __syncthreads();   // prior phase done reading wbig

            // ---- stage Wq/Wk/Wv head slices + Wo column slice (16 KB) ----
            {
                float4* dst = (float4*)wbig;
                dst[tid]       = ((const float4*)(Wq + (hh*DH)*DM       ))[tid];
                dst[256 + tid] = ((const float4*)(Wq + (DM   + hh*DH)*DM))[tid];
                dst[512 + tid] = ((const float4*)(Wq + (2*DM + hh*DH)*DM))[tid];
                dst[768 + tid] = *(const float4*)(WoL + (tid>>2)*DM + hh*DH + (tid&3)*4);
            }
            __syncthreads();

            // ---- q projection: q[t] full after pair-exchange ----
            float qh[DH];
#pragma unroll
            for (int t = 0; t < DH; ++t) {
                const float4* wq = (const float4*)(wbig + t*DM + hofs);
                float p0 = 0.f, p1 = 0.f;
#pragma unroll
                for (int i4 = 0; i4 < 8; ++i4) {
                    float4 ww = wq[i4];
                    p0 = fmaf(h[i4*4+0], ww.x, p0);
                    p1 = fmaf(h[i4*4+1], ww.y, p1);
                    p0 = fmaf(h[i4*4+2], ww.z, p0);
                    p1 = fmaf(h[i4*4+3], ww.w, p1);
                }
                float p = p0 + p1;
                p += __shfl_xor(p, 32, 64);
                qh[t] = (p + bq[hh*DH + t]) * 0.25f;   // fold 1/sqrt(Dh)
            }

            // ---- k,v rows -> kv LDS (pair computes full k_t, v_t) ----
            for (int t = 0; t < DH; ++t) {
                const float4* wk = (const float4*)(wbig + 1024 + t*DM + hofs);
                const float4* wv = (const float4*)(wbig + 2048 + t*DM + hofs);
                float k0 = 0.f, k1 = 0.f, v0 = 0.f, v1 = 0.f;
#pragma unroll
                for (int i4 = 0; i4 < 8; ++i4) {
                    float4 a4 = wk[i4], b4 = wv[i4];
                    k0 = fmaf(h[i4*4+0], a4.x, k0);
                    k1 = fmaf(h[i4*4+1], a4.y, k1);
                    k0 = fmaf(h[i4*4+2], a4.z, k0);
                    k1 = fmaf(h[i4*4+3], a4.w, k1);
                    v0 = fmaf(h[i4*4+0], b4.x, v0);
                    v1 = fmaf(h[i4*4+1], b4.y, v1);
                    v0 = fmaf(h[i4*4+2], b4.z, v0);
                    v1 = fmaf(h[i4*4+3], b4.w, v1);
                }
                float kp = k0 + k1; kp += __shfl_xor(kp, 32, 64);
                float vp = v0 + v1; vp += __shfl_xor(vp, 32, 64);
                kp += bq[DM   + hh*DH + t];
                vp += bq[2*DM + hh*DH + t];
                // half 0 lanes own the k row, half 1 lanes the v row
                float* dst = half ? &kvV[w][tok][t] : &kvK[w][tok][t];
                *dst = half ? vp : kp;
            }
            // kv written & read by the SAME wave: lgkmcnt ordering suffices.

            // ---- scores: this lane covers kx = half*16 .. +16 ----
            float sc[16];
            float mx = -1e30f;
#pragma unroll
            for (int j = 0; j < 16; ++j) {
                const float4* kr = (const float4*)&kvK[w][half*16 + j][0];
                float s0 = 0.f, s1 = 0.f;
#pragma unroll
                for (int t4 = 0; t4 < 4; ++t4) {
                    float4 k4 = kr[t4];
                    s0 = fmaf(qh[t4*4+0], k4.x, s0);
                    s1 = fmaf(qh[t4*4+1], k4.y, s1);
                    s0 = fmaf(qh[t4*4+2], k4.z, s0);
                    s1 = fmaf(qh[t4*4+3], k4.w, s1);
                }
                sc[j] = s0 + s1;
                mx = fmaxf(mx, sc[j]);
            }
            mx = fmaxf(mx, __shfl_xor(mx, 32, 64));
            float den = 0.f;
#pragma unroll
            for (int j = 0; j < 16; ++j) {
                float e = expf(sc[j] - mx);
                sc[j] = e; den += e;
            }
            den += __shfl_xor(den, 32, 64);
            const float inv = 1.f / den;

            // ---- PV: partial over my 16 kx, then pair-combine ----
            float oh[DH];
#pragma unroll
            for (int t = 0; t < DH; ++t) oh[t] = 0.f;
#pragma unroll
            for (int j = 0; j < 16; ++j) {
                const float wgt = sc[j] * inv;
                const float4* vr = (const float4*)&kvV[w][half*16 + j][0];
#pragma unroll
                for (int t4 = 0; t4 < 4; ++t4) {
                    float4 v4 = vr[t4];
                    oh[t4*4+0] = fmaf(wgt, v4.x, oh[t4*4+0]);
                    oh[t4*4+1] = fmaf(wgt, v4.y, oh[t4*4+1]);
                    oh[t4*4+2] = fmaf(wgt, v4.z, oh[t4*4+2]);
                    oh[t4*4+3] = fmaf(wgt, v4.w, oh[t4*4+3]);
                }
            }
#pragma unroll
            for (int t = 0; t < DH; ++t) oh[t] += __shfl_xor(oh[t], 32, 64);

            // ---- fold o-head into xacc via staged Wo slice ----
#pragma unroll
            for (int i = 0; i < 32; ++i) {
                const float4* w4 = (const float4*)(wbig + 3072 + (hofs + i)*DH);
                float4 wa = w4[0], wb = w4[1], wc = w4[2], wd = w4[3];
                float s0 = 0.f, s1 = 0.f;
                s0 = fmaf(oh[0],  wa.x, s0); s1 = fmaf(oh[1],  wa.y, s1);
                s0 = fmaf(oh[2],  wa.z, s0); s1 = fmaf(oh[3],  wa.w, s1);
                s0 = fmaf(oh[4],  wb.x, s0); s1 = fmaf(oh[5],  wb.y, s1);
                s0 = fmaf(oh[6],  wb.z, s0); s1 = fmaf(oh[7],  wb.w, s1);
                s0 = fmaf(oh[8],  wc.x, s0); s1 = fmaf(oh[9],  wc.y, s1);
                s0 = fmaf(oh[10], wc.z, s0); s1 = fmaf(oh[11], wc.w, s1);
                s0 = fmaf(oh[12], wd.x, s0); s1 = fmaf(oh[13], wd.y, s1);
                s0 = fmaf(oh[14], wd.z, s0); s1 = fmaf(oh[15], wd.w, s1);
                xacc[i] += s0 + s1;
            }
        }

        // ---- LN1 (pair-combined stats over 64 dims) ----
        {
            float s = 0.f;
#pragma unroll
            for (int i = 0; i < 32; ++i) s += xacc[i];
            s += __shfl_xor(s, 32, 64);
            const float mean = s * (1.f/DM);
            float v = 0.f;
#pragma unroll
            for (int i = 0; i < 32; ++i) { float dx = xacc[i]-mean; v = fmaf(dx,dx,v); }
            v += __shfl_xor(v, 32, 64);
            const float rs = rsqrtf(v * (1.f/DM) + 1e-5f);
#pragma unroll
            for (int i = 0; i < 32; ++i)
                h[i] = (xacc[i]-mean)*rs*ln1g[l*DM+hofs+i] + ln1b[l*DM+hofs+i];
        }

        // ---- FF in f-quarters ----
        float a2[32];
#pragma unroll
        for (int i = 0; i < 32; ++i) a2[i] = h[i] + b2w[l*DM + hofs + i];
        const float* W1L = W1w + l*DFF*DM;
        const float* W2L = W2w + l*DM*DFF;
        for (int f0 = 0; f0 < DFF; f0 += 32) {
            __syncthreads();   // prior wbig readers done
            {
                float4* dst = (float4*)wbig;
                const float4* s1p = (const float4*)(W1L + f0*DM);
                dst[tid]       = s1p[tid];
                dst[256 + tid] = s1p[256 + tid];
                int g = tid;
                dst[512 + g] = *(const float4*)(W2L + (g>>3)*DFF + f0 + (g&7)*4);
                g = tid + 256;
                dst[512 + g] = *(const float4*)(W2L + (g>>3)*DFF + f0 + (g&7)*4);
            }
            __syncthreads();

            for (int fc0 = 0; fc0 < 32; fc0 += 8) {
                float a[8];
#pragma unroll
                for (int fc = 0; fc < 8; ++fc) {
                    const float4* w14 = (const float4*)(wbig + (fc0+fc)*DM + hofs);
                    float p0 = 0.f, p1 = 0.f;
#pragma unroll
                    for (int i4 = 0; i4 < 8; ++i4) {
                        float4 ww = w14[i4];
                        p0 = fmaf(h[i4*4+0], ww.x, p0);
                        p1 = fmaf(h[i4*4+1], ww.y, p1);
                        p0 = fmaf(h[i4*4+2], ww.z, p0);
                        p1 = fmaf(h[i4*4+3], ww.w, p1);
                    }
                    float p = p0 + p1;
                    p += __shfl_xor(p, 32, 64);
                    a[fc] = fmaxf(p + b1w[l*DFF + f0 + fc0 + fc], 0.f);
                }
#pragma unroll
                for (int i = 0; i < 32; ++i) {
                    const float4* w24 = (const float4*)(wbig + 2048 + (hofs+i)*32 + fc0);
                    float4 wa = w24[0], wb = w24[1];
                    float u0 = fmaf(a[0], wa.x, fmaf(a[1], wa.y, fmaf(a[2], wa.z, a[3]*wa.w)));
                    float u1 = fmaf(a[4], wb.x, fmaf(a[5], wb.y, fmaf(a[6], wb.z, a[7]*wb.w)));
                    a2[i] += u0 + u1;
                }
            }
        }

        // ---- LN2 ----
        {
            float s = 0.f;
#pragma unroll
            for (int i = 0; i < 32; ++i) s += a2[i];
            s += __shfl_xor(s, 32, 64);
            const float mean = s * (1.f/DM);
            float v = 0.f;
#pragma unroll
            for (int i = 0; i < 32; ++i) { float dx = a2[i]-mean; v = fmaf(dx,dx,v); }
            v += __shfl_xor(v, 32, 64);
            const float rs = rsqrtf(v * (1.f/DM) + 1e-5f);
#pragma unroll
            for (int i = 0; i < 32; ++i)
                h[i] = (a2[i]-mean)*rs*ln2g[l*DM+hofs+i] + ln2b[l*DM+hofs+i];
        }
    }

    // ================= head =================
    // token-mean: butterfly within each 32-lane half (all 32 tokens)
    float hm[32];
#pragma unroll
    for (int i = 0; i < 32; ++i) {
        float v = h[i];
        v += __shfl_xor(v, 1,  64);
        v += __shfl_xor(v, 2,  64);
        v += __shfl_xor(v, 4,  64);
        v += __shfl_xor(v, 8,  64);
        v += __shfl_xor(v, 16, 64);
        hm[i] = v * (1.f/KTOK);
    }
    {
        float s = 0.f;
#pragma unroll
        for (int i = 0; i < 32; ++i) s += hm[i];
        s += __shfl_xor(s, 32, 64);
        const float mean = s * (1.f/DM);
        float v = 0.f;
#pragma unroll
        for (int i = 0; i < 32; ++i) { float dx = hm[i]-mean; v = fmaf(dx,dx,v); }
        v += __shfl_xor(v, 32, 64);
        const float rs = rsqrtf(v * (1.f/DM) + 1e-5f);
#pragma unroll
        for (int i = 0; i < 32; ++i)
            hm[i] = (hm[i]-mean)*rs*hg[hofs+i] + hb[hofs+i];
    }

    // head MLP: lane-pair (tok, tok+32) jointly computes GELU rows tok and tok+32
    float pA = 0.f, pB = 0.f;
    {
        const float4* wA = (const float4*)(hW1 + tok*DM + hofs);
        const float4* wB = (const float4*)(hW1 + (tok+32)*DM + hofs);
#pragma unroll
        for (int i4 = 0; i4 < 8; ++i4) {
            float4 a4 = wA[i4], b4 = wB[i4];
            pA = fmaf(hm[i4*4+0], a4.x, pA);
            pA = fmaf(hm[i4*4+1], a4.y, pA);
            pA = fmaf(hm[i4*4+2], a4.z, pA);
            pA = fmaf(hm[i4*4+3], a4.w, pA);
            pB = fmaf(hm[i4*4+0], b4.x, pB);
            pB = fmaf(hm[i4*4+1], b4.y, pB);
            pB = fmaf(hm[i4*4+2], b4.z, pB);
            pB = fmaf(hm[i4*4+3], b4.w, pB);
        }
    }
    pA += __shfl_xor(pA, 32, 64);
    pB += __shfl_xor(pB, 32, 64);
    const float aA = pA + hb1[tok];
    const float aB = pB + hb1[tok+32];
    const float gA = 0.5f * aA * (1.f + erff(aA * 0.70710678118654752f));
    const float gB = 0.5f * aB * (1.f + erff(aB * 0.70710678118654752f));
    float acc = fmaf(gA, hW2[tok], gB * hW2[tok+32]);   // both halves identical
    acc += __shfl_xor(acc, 1,  64);
    acc += __shfl_xor(acc, 2,  64);
    acc += __shfl_xor(acc, 4,  64);
    acc += __shfl_xor(acc, 8,  64);
    acc += __shfl_xor(acc, 16, 64);

    if (lane == 0) out[b] = acc + hb2[0];
}

extern "C" void kernel_launch(void* const* d_in, const int* in_sizes, int n_in,
                              void* d_out, int out_size, void* d_ws, size_t ws_size,
                              hipStream_t stream) {
    const int*   qidx   = (const int*)  d_in[0];
    const int*   offs   = (const int*)  d_in[1];
    const float* vals   = (const float*)d_in[2];
    // d_in[3] coords: unused by the reference
    const float* gscale = (const float*)d_in[4];
    const int*   NxP    = (const int*)  d_in[5];
    const int*   NyP    = (const int*)  d_in[6];
    const int*   NtP    = (const int*)  d_in[7];
    const float* lgam   = (const float*)d_in[8];
    const float* Wp     = (const float*)d_in[9];
    const float* bp     = (const float*)d_in[10];
    const float* Wqkv   = (const float*)d_in[11];
    const float* bqkv   = (const float*)d_in[12];
    const float* Wo     = (const float*)d_in[13];
    const float* bo     = (const float*)d_in[14];
    const float* W1w    = (const float*)d_in[15];
    const float* b1w    = (const float*)d_in[16];
    const float* W2w    = (const float*)d_in[17];
    const float* b2w    = (const float*)d_in[18];
    const float* ln1g   = (const float*)d_in[19];
    const float* ln1b   = (const float*)d_in[20];
    const float* ln2g   = (const float*)d_in[21];
    const float* ln2b   = (const float*)d_in[22];
    const float* hg     = (const float*)d_in[23];
    const float* hb     = (const float*)d_in[24];
    const float* hW1    = (const float*)d_in[25];
    const float* hb1    = (const float*)d_in[26];
    const float* hW2    = (const float*)d_in[27];
    const float* hb2    = (const float*)d_in[28];
    float* outp = (float*)d_out;

    const int B = in_sizes[0];
    dim3 grid(B / QB), block(256);
    hipLaunchKernelGGL(ff_kernel, grid, block, 0, stream,
        qidx, offs, vals, gscale, NxP, NyP, NtP, lgam,
        Wp, bp, Wqkv, bqkv, Wo, bo, W1w, b1w, W2w, b2w,
        ln1g, ln1b, ln2g, ln2b, hg, hb, hW1, hb1, hW2, hb2, outp);
}